// Round 15
// baseline (570.612 us; speedup 1.0000x reference)
//
#include <hip/hip_runtime.h>

typedef unsigned short u16;
typedef unsigned int u32;
typedef __bf16 bf16x8 __attribute__((ext_vector_type(8)));
typedef unsigned short u16x8 __attribute__((ext_vector_type(8)));
typedef float f32x4 __attribute__((ext_vector_type(4)));

#define S_LEN 2048
#define NH 16
#define HD 128

#define AS1 __attribute__((address_space(1)))
#define AS3 __attribute__((address_space(3)))

__device__ __forceinline__ u16 f2bf(float x) {
  u32 u = __builtin_bit_cast(u32, x);
  u32 r = u + 0x7FFFu + ((u >> 16) & 1u);  // RNE
  return (u16)(r >> 16);
}
__device__ __forceinline__ float bf2f(u16 b) {
  return __builtin_bit_cast(float, (u32)b << 16);
}

// ---------------- prep: all fp32->bf16 conversions + RoPE table, one launch -
__global__ void prep_all(const float* __restrict__ x, const float* __restrict__ wqkv,
                         const float* __restrict__ wo, u16* __restrict__ xb,
                         u16* __restrict__ wqb, u16* __restrict__ wob,
                         float* __restrict__ tab) {
  int blk = blockIdx.x;
  if (blk < 32768) {
    int i = blk * 256 + threadIdx.x;   // quad index
    const float* src; u16* dst;
    if (i < 4194304) { src = x; dst = xb; }
    else if (i < 7340032) { i -= 4194304; src = wqkv; dst = wqb; }
    else { i -= 7340032; src = wo; dst = wob; }
    float4 v = ((const float4*)src)[i];
    ushort4 o;
    o.x = f2bf(v.x); o.y = f2bf(v.y); o.z = f2bf(v.z); o.w = f2bf(v.w);
    ((ushort4*)dst)[i] = o;
  } else {
    int t = (blk - 32768) * 256 + threadIdx.x;  // [0, 131072)
    int s = t >> 6, j = t & 63;
    float inv = exp2f(-(float)j * 0.20762050593045083f);
    float ang = (float)s * inv;
    tab[t] = cosf(ang);
    tab[131072 + t] = sinf(ang);
  }
}

// ---------------- GEMM: C[M,N] = A[M,K]*B[N,K]^T (bt6 loop, fused epilogue) --
// 256x256 tile, BK=64, 8 waves (2x4), LDS 128KiB dbuf2, conflict-free 3-bit
// row-XOR swizzle. ds_reads pipelined one phase ahead (aP/aQ, lgkmcnt(4));
// read-order-proven distance-2 staging into the live buffer; vmcnt(7).
// NTILES=3 (GEMM1): persistent block processes 3 bx-adjacent tiles sharing
// the A panel (L2 reuse, 2 fewer pipeline drains). EPI=1: RoPE + V-transpose
// fused epilogue. EPI=0: plain C store.
__device__ __forceinline__ void storeC(u16* p, float v) { *p = f2bf(v); }
__device__ __forceinline__ void storeC(float* p, float v) { *p = v; }

template <int EPI, int NTILES, typename OutT>
__global__ __launch_bounds__(512, 2) void gemm_fused(const u16* __restrict__ A, const u16* __restrict__ B,
                                                     OutT* __restrict__ C, const float* __restrict__ tab,
                                                     u16* __restrict__ Qr, u16* __restrict__ Kr,
                                                     u16* __restrict__ Vt,
                                                     int M, int N, int K, int nbx) {
  __shared__ alignas(16) u16 LDS[65536];  // 128 KiB
  char* lds = (char*)LDS;
  const int tid = threadIdx.x;
  const int lane = tid & 63;
  const int w = tid >> 6;              // 0..7
  const int wr = w >> 2, wc = w & 3;   // 2 x 4 wave grid
  const int g = lane >> 4, c = lane & 15;

  const int nwg = gridDim.x;
  const int id = blockIdx.x;
  const int sw = (id & 7) * (nwg >> 3) + (id >> 3);

  const int half = w & 1;
  const int sub = (w >> 1) & 3;
  const size_t ldb = (size_t)K * 2;
  const int srow = lane >> 3;
  const int soff = ((lane & 7) ^ srow) << 4;   // inverse 3-bit row-XOR
  const int dq32 = (wc & 1) * 32;
  const int swz = (c & 7) << 4;
  const int NT = K >> 6;  // BK=64

#pragma unroll 1
  for (int ti = 0; ti < NTILES; ++ti) {
    int bx, by;
    if (NTILES == 3) { by = sw >> 3; bx = (sw & 7) * 3 + ti; }
    else             { bx = sw % nbx; by = sw / nbx; }
    const size_t rowBase = (size_t)by * 256;
    const size_t colBase = (size_t)bx * 256;

    const char* ApS = (const char*)A + (rowBase + half * 128 + srow) * ldb + soff;
    const char* BpS = (const char*)B + (colBase + half * 128 + srow) * ldb + soff;

    auto stA = [&](int u, int blk) {
      const int r0 = blk * 32 + sub * 8;
      const int dst = ((u & 1) * 2 + half) * 16384 + r0 * 128;
      __builtin_amdgcn_global_load_lds((const AS1 void*)(ApS + (size_t)r0 * ldb + (size_t)u * 128),
                                       (AS3 void*)(lds + dst), 16, 0, 0);
    };
    auto stB = [&](int u, int jj) {
      const int r0 = (sub * 4 + jj) * 8;
      const int dst = 65536 + ((u & 1) * 2 + half) * 16384 + r0 * 128;
      __builtin_amdgcn_global_load_lds((const AS1 void*)(BpS + (size_t)r0 * ldb + (size_t)u * 128),
                                       (AS3 void*)(lds + dst), 16, 0, 0);
    };
    auto rdA = [&](int bA, int mi, int kk) -> bf16x8 {
      return *(const bf16x8*)(lds + bA + mi * 2048 + c * 128 + ((kk * 64 + g * 16) ^ swz));
    };
    auto rdB = [&](int bB, int n, int kk) -> bf16x8 {
      int row_l;
      if (EPI) row_l = dq32 + (n & 1) * 16 + ((n >= 2) ? 64 : 0) + c;
      else     row_l = (wc & 1) * 64 + n * 16 + c;
      return *(const bf16x8*)(lds + bB + row_l * 128 + ((kk * 64 + g * 16) ^ swz));
    };

    f32x4 acc[8][4];
#pragma unroll
    for (int m = 0; m < 8; ++m)
#pragma unroll
      for (int n = 0; n < 4; ++n) acc[m][n] = f32x4{0.f, 0.f, 0.f, 0.f};

    bf16x8 bf_[4][2];
    bf16x8 aP[4], aQ[4];

    auto loadA = [&](bf16x8 (&s)[4], int bA, int mi) {
      s[0] = rdA(bA, mi, 0); s[1] = rdA(bA, mi, 1);
      s[2] = rdA(bA, mi + 1, 0); s[3] = rdA(bA, mi + 1, 1);
    };
    auto loadR1 = [&](int bA, int bB) {
      loadA(aP, bA, 0);
#pragma unroll
      for (int n = 0; n < 4; ++n) { bf_[n][0] = rdB(bB, n, 0); bf_[n][1] = rdB(bB, n, 1); }
    };
    auto MFMA2 = [&](int mi, bf16x8 (&s)[4]) {
#pragma unroll
      for (int n = 0; n < 4; ++n) {
        acc[mi][n]     = __builtin_amdgcn_mfma_f32_16x16x32_bf16(s[0], bf_[n][0], acc[mi][n], 0, 0, 0);
        acc[mi][n]     = __builtin_amdgcn_mfma_f32_16x16x32_bf16(s[1], bf_[n][1], acc[mi][n], 0, 0, 0);
        acc[mi + 1][n] = __builtin_amdgcn_mfma_f32_16x16x32_bf16(s[2], bf_[n][0], acc[mi + 1][n], 0, 0, 0);
        acc[mi + 1][n] = __builtin_amdgcn_mfma_f32_16x16x32_bf16(s[3], bf_[n][1], acc[mi + 1][n], 0, 0, 0);
      }
    };

    // protect previous tile's V-epilogue LDS scratch from restaging
    if (NTILES > 1 && ti > 0) __syncthreads();

#pragma unroll
    for (int b = 0; b < 4; ++b) stA(0, b);
#pragma unroll
    for (int j = 0; j < 4; ++j) stB(0, j);
#pragma unroll
    for (int b = 0; b < 4; ++b) stA(1, b);
#pragma unroll
    for (int j = 0; j < 4; ++j) stB(1, j);
    asm volatile("s_waitcnt vmcnt(8)" ::: "memory");
    __builtin_amdgcn_s_barrier();
    {
      const int bA0 = wr * 16384;
      const int bB0 = 65536 + (wc >> 1) * 16384;
      loadR1(bA0, bB0);
    }

#pragma unroll 1
    for (int t = 0; t < NT; ++t) {
      const int bA = (t & 1) * 32768 + wr * 16384;
      const int bB = 65536 + (t & 1) * 32768 + (wc >> 1) * 16384;
      loadA(aQ, bA, 2);
      if (t >= 1 && t + 1 < NT) stA(t + 1, 3);
      asm volatile("s_waitcnt lgkmcnt(4)" ::: "memory");
      __builtin_amdgcn_sched_barrier(0);
      __builtin_amdgcn_s_setprio(1);
      MFMA2(0, aP);
      __builtin_amdgcn_s_setprio(0);
      __builtin_amdgcn_sched_barrier(0);
      __builtin_amdgcn_s_barrier();
      loadA(aP, bA, 4);
      if (t + 2 < NT) { stA(t + 2, 0); stB(t + 2, 0); stB(t + 2, 1); }
      asm volatile("s_waitcnt lgkmcnt(4)" ::: "memory");
      __builtin_amdgcn_sched_barrier(0);
      __builtin_amdgcn_s_setprio(1);
      MFMA2(2, aQ);
      __builtin_amdgcn_s_setprio(0);
      __builtin_amdgcn_sched_barrier(0);
      __builtin_amdgcn_s_barrier();
      loadA(aQ, bA, 6);
      if (t + 2 < NT) { stA(t + 2, 1); stB(t + 2, 2); stB(t + 2, 3); }
      asm volatile("s_waitcnt lgkmcnt(4)" ::: "memory");
      __builtin_amdgcn_sched_barrier(0);
      __builtin_amdgcn_s_setprio(1);
      MFMA2(4, aP);
      __builtin_amdgcn_s_setprio(0);
      __builtin_amdgcn_sched_barrier(0);
      __builtin_amdgcn_s_barrier();
      if (t + 2 < NT) stA(t + 2, 2);
      asm volatile("s_waitcnt lgkmcnt(0)" ::: "memory");
      __builtin_amdgcn_sched_barrier(0);
      __builtin_amdgcn_s_setprio(1);
      MFMA2(6, aQ);
      __builtin_amdgcn_s_setprio(0);
      __builtin_amdgcn_sched_barrier(0);
      if (t + 2 < NT) { asm volatile("s_waitcnt vmcnt(7)" ::: "memory"); }
      else            { asm volatile("s_waitcnt vmcnt(0)" ::: "memory"); }
      __builtin_amdgcn_s_barrier();
      if (t + 1 < NT) {
        const int bA1 = ((t + 1) & 1) * 32768 + wr * 16384;
        const int bB1 = 65536 + ((t + 1) & 1) * 32768 + (wc >> 1) * 16384;
        loadR1(bA1, bB1);
      }
    }

    // ------------------------------- epilogue ------------------------------
    if (EPI == 0) {
#pragma unroll
      for (int m = 0; m < 8; ++m)
#pragma unroll
        for (int n = 0; n < 4; ++n) {
          size_t row = rowBase + wr * 128 + m * 16 + g * 4;
          size_t col = colBase + wc * 64 + n * 16 + c;
#pragma unroll
          for (int r = 0; r < 4; ++r)
            storeC(&C[(row + r) * (size_t)N + col], acc[m][n][r]);
        }
    } else {
      const int slot = (int)(colBase >> 11);                 // 0=q 1=k 2=v
      const int h = (((int)colBase >> 7) & 15) + (wc >> 1);
      const int bidx = (int)(rowBase >> 11);
      const int sbase = ((int)rowBase & 2047) + wr * 128;

      if (slot < 2) {
        u16* dst = (slot == 0 ? Qr : Kr) + (size_t)(bidx * NH + h) * S_LEN * HD;
#pragma unroll
        for (int m = 0; m < 8; ++m)
#pragma unroll
          for (int r = 0; r < 4; ++r) {
            const int s = sbase + m * 16 + g * 4 + r;
            u16* drow = dst + (size_t)s * HD;
            const float* tc = tab + s * 64;
            const float* ts = tab + 131072 + s * 64;
#pragma unroll
            for (int n = 0; n < 2; ++n) {
              const int dlo = dq32 + n * 16 + c;
              float cs = tc[dlo], sn = ts[dlo];
              float xlo = acc[m][n][r], xhi = acc[m][n + 2][r];
              drow[dlo]      = f2bf(cs * xlo - sn * xhi);
              drow[dlo + 64] = f2bf(cs * xhi + sn * xlo);
            }
          }
      } else {
        char* lv = lds + w * 16384;
#pragma unroll
        for (int m = 0; m < 8; ++m)
#pragma unroll
          for (int n = 0; n < 4; ++n) {
            const int ld = ((n >= 2) ? 32 : 0) + (n & 1) * 16 + c;
            ushort4 pk;
            pk.x = f2bf(acc[m][n][0]); pk.y = f2bf(acc[m][n][1]);
            pk.z = f2bf(acc[m][n][2]); pk.w = f2bf(acc[m][n][3]);
            *(ushort4*)(lv + ld * 256 + ((m * 32 + g * 8) ^ ((ld & 7) << 4))) = pk;
          }
        u16* vbase = Vt + (size_t)(bidx * NH + h) * HD * S_LEN;
#pragma unroll
        for (int rr = 0; rr < 16; ++rr) {
          const int ld = rr * 4 + (lane >> 4);
          const int d = dq32 + ld + ((rr >= 8) ? 32 : 0);
          u16x8 v = *(const u16x8*)(lv + ld * 256 + (((lane & 15) * 16) ^ ((ld & 7) << 4)));
          *(u16x8*)(vbase + (size_t)d * S_LEN + sbase + (lane & 15) * 8) = v;
        }
      }
    }
  }
}

// ---------------- causal flash attention: 8 waves x 32 q-rows ---------------
__global__ __launch_bounds__(512, 2) void attn_fwd(const u16* __restrict__ Q, const u16* __restrict__ K,
                                                   const u16* __restrict__ Vt, u16* __restrict__ O) {
  __shared__ alignas(16) u16 Ks[2 * 64 * 128];   // 32 KiB
  __shared__ alignas(16) u16 Vs[2 * 128 * 64];   // 32 KiB
  __shared__ alignas(16) u16 Pl[8 * 32 * 64];    // 32 KiB
  const int tid = threadIdx.x;
  const int lane = tid & 63;
  const int w = tid >> 6;
  const int g = lane >> 4, c = lane & 15;
  const int bh = blockIdx.x;
  const int pair = blockIdx.y;    // 0..3
  const int b = bh >> 4, h = bh & 15;

  const u16* Qb = Q + (size_t)bh * S_LEN * HD;
  const u16* Kb = K + (size_t)bh * S_LEN * HD;
  const u16* Vb = Vt + (size_t)bh * HD * S_LEN;
  const float SL = 0.12751753f;   // (1/sqrt(128)) * log2(e)
  const int swz = (c & 7) << 4;

  int ldsOff[2], srcK[2], srcV[2];
#pragma unroll
  for (int ii = 0; ii < 2; ++ii) {
    int p = (w * 2 + ii) * 1024 + lane * 16;
    ldsOff[ii] = p;
    int rk = p >> 8, ik = p & 255;
    srcK[ii] = rk * 256 + (ik ^ ((rk & 7) << 4));
    int rv = p >> 7, iv = p & 127;
    srcV[ii] = rv * (S_LEN * 2) + (iv ^ ((rv & 7) << 4));
  }
  int koff[4], voff[2];
#pragma unroll
  for (int kb = 0; kb < 4; ++kb) koff[kb] = (kb * 64 + g * 16) ^ swz;
  voff[0] = (g * 16) ^ swz;
  voff[1] = (64 + g * 16) ^ swz;
  int poff[4];
#pragma unroll
  for (int t = 0; t < 4; ++t) poff[t] = (t * 32 + g * 8) ^ swz;
  char* Pw = (char*)Pl + w * 4096;

#pragma unroll 1
  for (int ph = 0; ph < 2; ++ph) {
    const int sti = ph ? (7 - pair) : pair;
    const int q0 = sti * 256 + w * 32;

    bf16x8 qf[2][4];
#pragma unroll
    for (int qh = 0; qh < 2; ++qh)
#pragma unroll
      for (int kb = 0; kb < 4; ++kb)
        qf[qh][kb] = *(const bf16x8*)&Qb[(size_t)(q0 + qh * 16 + c) * HD + kb * 32 + g * 8];

    f32x4 acc[2][8];
#pragma unroll
    for (int qh = 0; qh < 2; ++qh)
#pragma unroll
      for (int cb = 0; cb < 8; ++cb) acc[qh][cb] = f32x4{0.f, 0.f, 0.f, 0.f};
    float m_i[2] = {-3e38f, -3e38f}, l_i[2] = {0.f, 0.f};

    const int nsteps = sti * 4 + 4;
#pragma unroll
    for (int ii = 0; ii < 2; ++ii) {
      __builtin_amdgcn_global_load_lds((const AS1 void*)((const char*)Kb + srcK[ii]),
                                       (AS3 void*)((char*)Ks + ldsOff[ii] - lane * 16), 16, 0, 0);
      __builtin_amdgcn_global_load_lds((const AS1 void*)((const char*)Vb + srcV[ii]),
                                       (AS3 void*)((char*)Vs + ldsOff[ii] - lane * 16), 16, 0, 0);
    }
    __syncthreads();
    int cur = 0;

#pragma unroll 1
    for (int st = 0; st < nsteps; ++st) {
      const int kv0 = st << 6;
      if (st + 1 < nsteps) {
        const char* kbase = (const char*)Kb + (size_t)(kv0 + 64) * 256;
        const char* vbase = (const char*)Vb + (size_t)(kv0 + 64) * 2;
        const int nb = (cur ^ 1) * 16384;
#pragma unroll
        for (int ii = 0; ii < 2; ++ii) {
          __builtin_amdgcn_global_load_lds((const AS1 void*)(kbase + srcK[ii]),
                                           (AS3 void*)((char*)Ks + nb + ldsOff[ii] - lane * 16), 16, 0, 0);
          __builtin_amdgcn_global_load_lds((const AS1 void*)(vbase + srcV[ii]),
                                           (AS3 void*)((char*)Vs + nb + ldsOff[ii] - lane * 16), 16, 0, 0);
        }
      }
      if (kv0 < q0 + 32) {
        const char* Kt = (const char*)Ks + cur * 16384;
        const char* Vtl = (const char*)Vs + cur * 16384;
        f32x4 s[2][4];
#pragma unroll
        for (int qh = 0; qh < 2; ++qh)
#pragma unroll
          for (int t = 0; t < 4; ++t) s[qh][t] = f32x4{0.f, 0.f, 0.f, 0.f};
#pragma unroll
        for (int t = 0; t < 4; ++t)
#pragma unroll
          for (int kb = 0; kb < 4; ++kb) {
            bf16x8 kf = *(const bf16x8*)(Kt + t * 4096 + c * 256 + koff[kb]);
            s[0][t] = __builtin_amdgcn_mfma_f32_16x16x32_bf16(kf, qf[0][kb], s[0][t], 0, 0, 0);
            s[1][t] = __builtin_amdgcn_mfma_f32_16x16x32_bf16(kf, qf[1][kb], s[1][t], 0, 0, 0);
          }
        if (kv0 + 63 > q0) {
#pragma unroll
          for (int qh = 0; qh < 2; ++qh) {
            const int lim = q0 + qh * 16 + c - kv0 - 4 * g;
#pragma unroll
            for (int t = 0; t < 4; ++t)
#pragma unroll
              for (int r = 0; r < 4; ++r)
                s[qh][t][r] = (16 * t + r <= lim) ? s[qh][t][r] : -3e38f;
          }
        }
        float ar[2][4];
#pragma unroll
        for (int qh = 0; qh < 2; ++qh) {
          float mx = s[qh][0][0];
#pragma unroll
          for (int t = 0; t < 4; ++t)
#pragma unroll
            for (int r = 0; r < 4; ++r) mx = fmaxf(mx, s[qh][t][r]);
          mx = fmaxf(mx, __shfl_xor(mx, 16));
          mx = fmaxf(mx, __shfl_xor(mx, 32));
          const float mn = fmaxf(m_i[qh], mx);
          const float alpha = exp2f((m_i[qh] - mn) * SL);
          float rs = 0.f;
#pragma unroll
          for (int t = 0; t < 4; ++t) {
            float p0 = exp2f((s[qh][t][0] - mn) * SL);
            float p1 = exp2f((s[qh][t][1] - mn) * SL);
            float p2 = exp2f((s[qh][t][2] - mn) * SL);
            float p3 = exp2f((s[qh][t][3] - mn) * SL);
            rs += (p0 + p1) + (p2 + p3);
            ushort4 pw;
            pw.x = f2bf(p0); pw.y = f2bf(p1); pw.z = f2bf(p2); pw.w = f2bf(p3);
            *(ushort4*)(Pw + (qh * 16 + c) * 128 + poff[t]) = pw;
          }
          rs += __shfl_xor(rs, 16);
          rs += __shfl_xor(rs, 32);
          l_i[qh] = l_i[qh] * alpha + rs;
          m_i[qh] = mn;
#pragma unroll
          for (int r = 0; r < 4; ++r) ar[qh][r] = __shfl(alpha, 4 * g + r);
        }
#pragma unroll
        for (int qh = 0; qh < 2; ++qh)
#pragma unroll
          for (int cb = 0; cb < 8; ++cb)
#pragma unroll
            for (int r = 0; r < 4; ++r) acc[qh][cb][r] *= ar[qh][r];
        bf16x8 pa[2][2];
#pragma unroll
        for (int qh = 0; qh < 2; ++qh) {
          pa[qh][0] = *(const bf16x8*)(Pw + (qh * 16 + c) * 128 + voff[0]);
          pa[qh][1] = *(const bf16x8*)(Pw + (qh * 16 + c) * 128 + voff[1]);
        }
#pragma unroll
        for (int cb = 0; cb < 8; ++cb) {
          bf16x8 vf0 = *(const bf16x8*)(Vtl + cb * 2048 + c * 128 + voff[0]);
          bf16x8 vf1 = *(const bf16x8*)(Vtl + cb * 2048 + c * 128 + voff[1]);
          acc[0][cb] = __builtin_amdgcn_mfma_f32_16x16x32_bf16(pa[0][0], vf0, acc[0][cb], 0, 0, 0);
          acc[0][cb] = __builtin_amdgcn_mfma_f32_16x16x32_bf16(pa[0][1], vf1, acc[0][cb], 0, 0, 0);
          acc[1][cb] = __builtin_amdgcn_mfma_f32_16x16x32_bf16(pa[1][0], vf0, acc[1][cb], 0, 0, 0);
          acc[1][cb] = __builtin_amdgcn_mfma_f32_16x16x32_bf16(pa[1][1], vf1, acc[1][cb], 0, 0, 0);
        }
      }
      __syncthreads();
      cur ^= 1;
    }
#pragma unroll
    for (int qh = 0; qh < 2; ++qh) {
      float linv = 1.0f / l_i[qh];
      float lr[4];
#pragma unroll
      for (int r = 0; r < 4; ++r) lr[r] = __shfl(linv, 4 * g + r);
#pragma unroll
      for (int cb = 0; cb < 8; ++cb)
#pragma unroll
        for (int r = 0; r < 4; ++r) {
          int q = q0 + qh * 16 + 4 * g + r;
          O[(((size_t)b * S_LEN + q) * NH + h) * HD + cb * 16 + c] = f2bf(acc[qh][cb][r] * lr[r]);
        }
    }
  }
}

// ---------------------------------------------------------------------------
extern "C" void kernel_launch(void* const* d_in, const int* in_sizes, int n_in,
                              void* d_out, int out_size, void* d_ws, size_t ws_size,
                              hipStream_t stream) {
  const float* x    = (const float*)d_in[0];
  const float* wqkv = (const float*)d_in[1];
  const float* wo   = (const float*)d_in[2];
  float* out = (float*)d_out;
  char* ws = (char*)d_ws;

  u16*  xb    = (u16*)(ws + 0);            // reused as attn out later
  u16*  wqkvb = (u16*)(ws + 33554432);
  float* tab  = (float*)(ws + 58720256);   // live through gemm1 epilogue
  u16*  wob   = (u16*)(ws + 67108864);     // ex-qkvb region (free)
  u16*  Vt    = (u16*)(ws + 167772160);
  u16*  attn  = (u16*)(ws + 0);
  u16*  Qr = (u16*)d_out;                  // d_out scratch: dead before GEMM2
  u16*  Kr = (u16*)d_out + 16777216;

  // all conversions + RoPE table in one launch
  prep_all<<<33280, 256, 0, stream>>>(x, wqkv, wo, xb, wqkvb, wob, tab);

  // qkv = x @ wqkv^T fused with RoPE + V-transpose (persistent: 3 tiles/block)
  gemm_fused<1, 3, u16><<<256, 512, 0, stream>>>(xb, wqkvb, (u16*)nullptr, tab, Qr, Kr, Vt,
                                                 8192, 6144, 2048, 24);

  attn_fwd<<<dim3(64, 4), 512, 0, stream>>>(Qr, Kr, Vt, attn);

  // out = attn @ wo^T
  gemm_fused<0, 1, float><<<256, 512, 0, stream>>>(attn, wob, out, nullptr, nullptr, nullptr, nullptr,
                                                   8192, 2048, 2048, 8);
}

// Round 16
// 401.395 us; speedup vs baseline: 1.4216x; 1.4216x over previous
//
#include <hip/hip_runtime.h>

typedef unsigned short u16;
typedef unsigned int u32;
typedef __bf16 bf16x8 __attribute__((ext_vector_type(8)));
typedef unsigned short u16x8 __attribute__((ext_vector_type(8)));
typedef float f32x4 __attribute__((ext_vector_type(4)));

#define S_LEN 2048
#define NH 16
#define HD 128

#define AS1 __attribute__((address_space(1)))
#define AS3 __attribute__((address_space(3)))

__device__ __forceinline__ u16 f2bf(float x) {
  u32 u = __builtin_bit_cast(u32, x);
  u32 r = u + 0x7FFFu + ((u >> 16) & 1u);  // RNE
  return (u16)(r >> 16);
}
__device__ __forceinline__ float bf2f(u16 b) {
  return __builtin_bit_cast(float, (u32)b << 16);
}

// ---------------- prep: all fp32->bf16 conversions + RoPE table, one launch -
__global__ void prep_all(const float* __restrict__ x, const float* __restrict__ wqkv,
                         const float* __restrict__ wo, u16* __restrict__ xb,
                         u16* __restrict__ wqb, u16* __restrict__ wob,
                         float* __restrict__ tab) {
  int blk = blockIdx.x;
  if (blk < 32768) {
    int i = blk * 256 + threadIdx.x;   // quad index
    const float* src; u16* dst;
    if (i < 4194304) { src = x; dst = xb; }
    else if (i < 7340032) { i -= 4194304; src = wqkv; dst = wqb; }
    else { i -= 7340032; src = wo; dst = wob; }
    float4 v = ((const float4*)src)[i];
    ushort4 o;
    o.x = f2bf(v.x); o.y = f2bf(v.y); o.z = f2bf(v.z); o.w = f2bf(v.w);
    ((ushort4*)dst)[i] = o;
  } else {
    int t = (blk - 32768) * 256 + threadIdx.x;  // [0, 131072)
    int s = t >> 6, j = t & 63;
    float inv = exp2f(-(float)j * 0.20762050593045083f);
    float ang = (float)s * inv;
    tab[t] = cosf(ang);
    tab[131072 + t] = sinf(ang);
  }
}

// ---------------- GEMM: C[M,N] = A[M,K]*B[N,K]^T (bt6 loop, fused epilogue) --
// 256x256 tile, BK=64, 8 waves (2x4), LDS 128KiB dbuf2, conflict-free 3-bit
// row-XOR swizzle. ds_reads pipelined one phase ahead (aP/aQ, lgkmcnt(4));
// read-order-proven distance-2 staging; boundary vmcnt(7). 768-block launch
// is load-bearing: >=2 resident blocks/CU provide the TLP that fills barrier
// stalls (round-15 lesson: 256 blocks = 1/CU -> MfmaUtil 43%->24%).
// EPI=1: RoPE + V-transpose fused epilogue. EPI=0: plain C store.
__device__ __forceinline__ void storeC(u16* p, float v) { *p = f2bf(v); }
__device__ __forceinline__ void storeC(float* p, float v) { *p = v; }

template <int EPI, typename OutT>
__global__ __launch_bounds__(512, 2) void gemm_fused(const u16* __restrict__ A, const u16* __restrict__ B,
                                                     OutT* __restrict__ C, const float* __restrict__ tab,
                                                     u16* __restrict__ Qr, u16* __restrict__ Kr,
                                                     u16* __restrict__ Vt,
                                                     int M, int N, int K, int nbx) {
  __shared__ alignas(16) u16 LDS[65536];  // 128 KiB
  char* lds = (char*)LDS;
  const int tid = threadIdx.x;
  const int lane = tid & 63;
  const int w = tid >> 6;              // 0..7
  const int wr = w >> 2, wc = w & 3;   // 2 x 4 wave grid
  const int g = lane >> 4, c = lane & 15;

  const int nwg = gridDim.x;
  const int id = blockIdx.x;
  const int sw = (id & 7) * (nwg >> 3) + (id >> 3);
  const int bx = sw % nbx, by = sw / nbx;
  const size_t rowBase = (size_t)by * 256;
  const size_t colBase = (size_t)bx * 256;

  const int half = w & 1;
  const int sub = (w >> 1) & 3;
  const size_t ldb = (size_t)K * 2;
  const int srow = lane >> 3;
  const int soff = ((lane & 7) ^ srow) << 4;   // inverse 3-bit row-XOR
  const char* ApS = (const char*)A + (rowBase + half * 128 + srow) * ldb + soff;
  const char* BpS = (const char*)B + (colBase + half * 128 + srow) * ldb + soff;

  auto stA = [&](int u, int blk) {
    const int r0 = blk * 32 + sub * 8;
    const int dst = ((u & 1) * 2 + half) * 16384 + r0 * 128;
    __builtin_amdgcn_global_load_lds((const AS1 void*)(ApS + (size_t)r0 * ldb + (size_t)u * 128),
                                     (AS3 void*)(lds + dst), 16, 0, 0);
  };
  auto stB = [&](int u, int jj) {
    const int r0 = (sub * 4 + jj) * 8;
    const int dst = 65536 + ((u & 1) * 2 + half) * 16384 + r0 * 128;
    __builtin_amdgcn_global_load_lds((const AS1 void*)(BpS + (size_t)r0 * ldb + (size_t)u * 128),
                                     (AS3 void*)(lds + dst), 16, 0, 0);
  };

  const int dq32 = (wc & 1) * 32;      // EPI=1 col permutation base
  const int swz = (c & 7) << 4;
  auto rdA = [&](int bA, int mi, int kk) -> bf16x8 {
    return *(const bf16x8*)(lds + bA + mi * 2048 + c * 128 + ((kk * 64 + g * 16) ^ swz));
  };
  auto rdB = [&](int bB, int n, int kk) -> bf16x8 {
    int row_l;
    if (EPI) row_l = dq32 + (n & 1) * 16 + ((n >= 2) ? 64 : 0) + c;
    else     row_l = (wc & 1) * 64 + n * 16 + c;
    return *(const bf16x8*)(lds + bB + row_l * 128 + ((kk * 64 + g * 16) ^ swz));
  };

  f32x4 acc[8][4];
#pragma unroll
  for (int m = 0; m < 8; ++m)
#pragma unroll
    for (int n = 0; n < 4; ++n) acc[m][n] = f32x4{0.f, 0.f, 0.f, 0.f};

  bf16x8 bf_[4][2];
  bf16x8 aP[4], aQ[4];

  auto loadA = [&](bf16x8 (&s)[4], int bA, int mi) {
    s[0] = rdA(bA, mi, 0); s[1] = rdA(bA, mi, 1);
    s[2] = rdA(bA, mi + 1, 0); s[3] = rdA(bA, mi + 1, 1);
  };
  auto loadR1 = [&](int bA, int bB) {
    loadA(aP, bA, 0);
#pragma unroll
    for (int n = 0; n < 4; ++n) { bf_[n][0] = rdB(bB, n, 0); bf_[n][1] = rdB(bB, n, 1); }
  };
  auto MFMA2 = [&](int mi, bf16x8 (&s)[4]) {
#pragma unroll
    for (int n = 0; n < 4; ++n) {
      acc[mi][n]     = __builtin_amdgcn_mfma_f32_16x16x32_bf16(s[0], bf_[n][0], acc[mi][n], 0, 0, 0);
      acc[mi][n]     = __builtin_amdgcn_mfma_f32_16x16x32_bf16(s[1], bf_[n][1], acc[mi][n], 0, 0, 0);
      acc[mi + 1][n] = __builtin_amdgcn_mfma_f32_16x16x32_bf16(s[2], bf_[n][0], acc[mi + 1][n], 0, 0, 0);
      acc[mi + 1][n] = __builtin_amdgcn_mfma_f32_16x16x32_bf16(s[3], bf_[n][1], acc[mi + 1][n], 0, 0, 0);
    }
  };

  const int NT = K >> 6;  // BK=64

#pragma unroll
  for (int b = 0; b < 4; ++b) stA(0, b);
#pragma unroll
  for (int j = 0; j < 4; ++j) stB(0, j);
#pragma unroll
  for (int b = 0; b < 4; ++b) stA(1, b);
#pragma unroll
  for (int j = 0; j < 4; ++j) stB(1, j);
  asm volatile("s_waitcnt vmcnt(8)" ::: "memory");
  __builtin_amdgcn_s_barrier();
  {
    const int bA0 = wr * 16384;
    const int bB0 = 65536 + (wc >> 1) * 16384;
    loadR1(bA0, bB0);
  }

#pragma unroll 1
  for (int t = 0; t < NT; ++t) {
    const int bA = (t & 1) * 32768 + wr * 16384;
    const int bB = 65536 + (t & 1) * 32768 + (wc >> 1) * 16384;
    loadA(aQ, bA, 2);
    if (t >= 1 && t + 1 < NT) stA(t + 1, 3);
    asm volatile("s_waitcnt lgkmcnt(4)" ::: "memory");
    __builtin_amdgcn_sched_barrier(0);
    __builtin_amdgcn_s_setprio(1);
    MFMA2(0, aP);
    __builtin_amdgcn_s_setprio(0);
    __builtin_amdgcn_sched_barrier(0);
    __builtin_amdgcn_s_barrier();
    loadA(aP, bA, 4);
    if (t + 2 < NT) { stA(t + 2, 0); stB(t + 2, 0); stB(t + 2, 1); }
    asm volatile("s_waitcnt lgkmcnt(4)" ::: "memory");
    __builtin_amdgcn_sched_barrier(0);
    __builtin_amdgcn_s_setprio(1);
    MFMA2(2, aQ);
    __builtin_amdgcn_s_setprio(0);
    __builtin_amdgcn_sched_barrier(0);
    __builtin_amdgcn_s_barrier();
    loadA(aQ, bA, 6);
    if (t + 2 < NT) { stA(t + 2, 1); stB(t + 2, 2); stB(t + 2, 3); }
    asm volatile("s_waitcnt lgkmcnt(4)" ::: "memory");
    __builtin_amdgcn_sched_barrier(0);
    __builtin_amdgcn_s_setprio(1);
    MFMA2(4, aP);
    __builtin_amdgcn_s_setprio(0);
    __builtin_amdgcn_sched_barrier(0);
    __builtin_amdgcn_s_barrier();
    if (t + 2 < NT) stA(t + 2, 2);
    asm volatile("s_waitcnt lgkmcnt(0)" ::: "memory");
    __builtin_amdgcn_sched_barrier(0);
    __builtin_amdgcn_s_setprio(1);
    MFMA2(6, aQ);
    __builtin_amdgcn_s_setprio(0);
    __builtin_amdgcn_sched_barrier(0);
    if (t + 2 < NT) { asm volatile("s_waitcnt vmcnt(7)" ::: "memory"); }
    else            { asm volatile("s_waitcnt vmcnt(0)" ::: "memory"); }
    __builtin_amdgcn_s_barrier();
    if (t + 1 < NT) {
      const int bA1 = ((t + 1) & 1) * 32768 + wr * 16384;
      const int bB1 = 65536 + ((t + 1) & 1) * 32768 + (wc >> 1) * 16384;
      loadR1(bA1, bB1);
    }
  }

  // ------------------------------- epilogue --------------------------------
  if (EPI == 0) {
#pragma unroll
    for (int m = 0; m < 8; ++m)
#pragma unroll
      for (int n = 0; n < 4; ++n) {
        size_t row = rowBase + wr * 128 + m * 16 + g * 4;
        size_t col = colBase + wc * 64 + n * 16 + c;
#pragma unroll
        for (int r = 0; r < 4; ++r)
          storeC(&C[(row + r) * (size_t)N + col], acc[m][n][r]);
      }
  } else {
    const int slot = (int)(colBase >> 11);                 // 0=q 1=k 2=v
    const int h = (((int)colBase >> 7) & 15) + (wc >> 1);
    const int bidx = (int)(rowBase >> 11);
    const int sbase = ((int)rowBase & 2047) + wr * 128;

    if (slot < 2) {
      u16* dst = (slot == 0 ? Qr : Kr) + (size_t)(bidx * NH + h) * S_LEN * HD;
#pragma unroll
      for (int m = 0; m < 8; ++m)
#pragma unroll
        for (int r = 0; r < 4; ++r) {
          const int s = sbase + m * 16 + g * 4 + r;
          u16* drow = dst + (size_t)s * HD;
          const float* tc = tab + s * 64;
          const float* ts = tab + 131072 + s * 64;
#pragma unroll
          for (int n = 0; n < 2; ++n) {
            const int dlo = dq32 + n * 16 + c;
            float cs = tc[dlo], sn = ts[dlo];
            float xlo = acc[m][n][r], xhi = acc[m][n + 2][r];
            drow[dlo]      = f2bf(cs * xlo - sn * xhi);
            drow[dlo + 64] = f2bf(cs * xhi + sn * xlo);
          }
        }
    } else {
      char* lv = lds + w * 16384;
#pragma unroll
      for (int m = 0; m < 8; ++m)
#pragma unroll
        for (int n = 0; n < 4; ++n) {
          const int ld = ((n >= 2) ? 32 : 0) + (n & 1) * 16 + c;
          ushort4 pk;
          pk.x = f2bf(acc[m][n][0]); pk.y = f2bf(acc[m][n][1]);
          pk.z = f2bf(acc[m][n][2]); pk.w = f2bf(acc[m][n][3]);
          *(ushort4*)(lv + ld * 256 + ((m * 32 + g * 8) ^ ((ld & 7) << 4))) = pk;
        }
      u16* vbase = Vt + (size_t)(bidx * NH + h) * HD * S_LEN;
#pragma unroll
      for (int rr = 0; rr < 16; ++rr) {
        const int ld = rr * 4 + (lane >> 4);
        const int d = dq32 + ld + ((rr >= 8) ? 32 : 0);
        u16x8 v = *(const u16x8*)(lv + ld * 256 + (((lane & 15) * 16) ^ ((ld & 7) << 4)));
        *(u16x8*)(vbase + (size_t)d * S_LEN + sbase + (lane & 15) * 8) = v;
      }
    }
  }
}

// ---------------- causal flash attention: 8 waves x 32 q-rows ---------------
__global__ __launch_bounds__(512, 2) void attn_fwd(const u16* __restrict__ Q, const u16* __restrict__ K,
                                                   const u16* __restrict__ Vt, u16* __restrict__ O) {
  __shared__ alignas(16) u16 Ks[2 * 64 * 128];   // 32 KiB
  __shared__ alignas(16) u16 Vs[2 * 128 * 64];   // 32 KiB
  __shared__ alignas(16) u16 Pl[8 * 32 * 64];    // 32 KiB
  const int tid = threadIdx.x;
  const int lane = tid & 63;
  const int w = tid >> 6;
  const int g = lane >> 4, c = lane & 15;
  const int bh = blockIdx.x;
  const int pair = blockIdx.y;    // 0..3
  const int b = bh >> 4, h = bh & 15;

  const u16* Qb = Q + (size_t)bh * S_LEN * HD;
  const u16* Kb = K + (size_t)bh * S_LEN * HD;
  const u16* Vb = Vt + (size_t)bh * HD * S_LEN;
  const float SL = 0.12751753f;   // (1/sqrt(128)) * log2(e)
  const int swz = (c & 7) << 4;

  int ldsOff[2], srcK[2], srcV[2];
#pragma unroll
  for (int ii = 0; ii < 2; ++ii) {
    int p = (w * 2 + ii) * 1024 + lane * 16;
    ldsOff[ii] = p;
    int rk = p >> 8, ik = p & 255;
    srcK[ii] = rk * 256 + (ik ^ ((rk & 7) << 4));
    int rv = p >> 7, iv = p & 127;
    srcV[ii] = rv * (S_LEN * 2) + (iv ^ ((rv & 7) << 4));
  }
  int koff[4], voff[2];
#pragma unroll
  for (int kb = 0; kb < 4; ++kb) koff[kb] = (kb * 64 + g * 16) ^ swz;
  voff[0] = (g * 16) ^ swz;
  voff[1] = (64 + g * 16) ^ swz;
  int poff[4];
#pragma unroll
  for (int t = 0; t < 4; ++t) poff[t] = (t * 32 + g * 8) ^ swz;
  char* Pw = (char*)Pl + w * 4096;

#pragma unroll 1
  for (int ph = 0; ph < 2; ++ph) {
    const int sti = ph ? (7 - pair) : pair;
    const int q0 = sti * 256 + w * 32;

    bf16x8 qf[2][4];
#pragma unroll
    for (int qh = 0; qh < 2; ++qh)
#pragma unroll
      for (int kb = 0; kb < 4; ++kb)
        qf[qh][kb] = *(const bf16x8*)&Qb[(size_t)(q0 + qh * 16 + c) * HD + kb * 32 + g * 8];

    f32x4 acc[2][8];
#pragma unroll
    for (int qh = 0; qh < 2; ++qh)
#pragma unroll
      for (int cb = 0; cb < 8; ++cb) acc[qh][cb] = f32x4{0.f, 0.f, 0.f, 0.f};
    float m_i[2] = {-3e38f, -3e38f}, l_i[2] = {0.f, 0.f};

    const int nsteps = sti * 4 + 4;
#pragma unroll
    for (int ii = 0; ii < 2; ++ii) {
      __builtin_amdgcn_global_load_lds((const AS1 void*)((const char*)Kb + srcK[ii]),
                                       (AS3 void*)((char*)Ks + ldsOff[ii] - lane * 16), 16, 0, 0);
      __builtin_amdgcn_global_load_lds((const AS1 void*)((const char*)Vb + srcV[ii]),
                                       (AS3 void*)((char*)Vs + ldsOff[ii] - lane * 16), 16, 0, 0);
    }
    __syncthreads();
    int cur = 0;

#pragma unroll 1
    for (int st = 0; st < nsteps; ++st) {
      const int kv0 = st << 6;
      if (st + 1 < nsteps) {
        const char* kbase = (const char*)Kb + (size_t)(kv0 + 64) * 256;
        const char* vbase = (const char*)Vb + (size_t)(kv0 + 64) * 2;
        const int nb = (cur ^ 1) * 16384;
#pragma unroll
        for (int ii = 0; ii < 2; ++ii) {
          __builtin_amdgcn_global_load_lds((const AS1 void*)(kbase + srcK[ii]),
                                           (AS3 void*)((char*)Ks + nb + ldsOff[ii] - lane * 16), 16, 0, 0);
          __builtin_amdgcn_global_load_lds((const AS1 void*)(vbase + srcV[ii]),
                                           (AS3 void*)((char*)Vs + nb + ldsOff[ii] - lane * 16), 16, 0, 0);
        }
      }
      if (kv0 < q0 + 32) {
        const char* Kt = (const char*)Ks + cur * 16384;
        const char* Vtl = (const char*)Vs + cur * 16384;
        f32x4 s[2][4];
#pragma unroll
        for (int qh = 0; qh < 2; ++qh)
#pragma unroll
          for (int t = 0; t < 4; ++t) s[qh][t] = f32x4{0.f, 0.f, 0.f, 0.f};
#pragma unroll
        for (int t = 0; t < 4; ++t)
#pragma unroll
          for (int kb = 0; kb < 4; ++kb) {
            bf16x8 kf = *(const bf16x8*)(Kt + t * 4096 + c * 256 + koff[kb]);
            s[0][t] = __builtin_amdgcn_mfma_f32_16x16x32_bf16(kf, qf[0][kb], s[0][t], 0, 0, 0);
            s[1][t] = __builtin_amdgcn_mfma_f32_16x16x32_bf16(kf, qf[1][kb], s[1][t], 0, 0, 0);
          }
        if (kv0 + 63 > q0) {
#pragma unroll
          for (int qh = 0; qh < 2; ++qh) {
            const int lim = q0 + qh * 16 + c - kv0 - 4 * g;
#pragma unroll
            for (int t = 0; t < 4; ++t)
#pragma unroll
              for (int r = 0; r < 4; ++r)
                s[qh][t][r] = (16 * t + r <= lim) ? s[qh][t][r] : -3e38f;
          }
        }
        float ar[2][4];
#pragma unroll
        for (int qh = 0; qh < 2; ++qh) {
          float mx = s[qh][0][0];
#pragma unroll
          for (int t = 0; t < 4; ++t)
#pragma unroll
            for (int r = 0; r < 4; ++r) mx = fmaxf(mx, s[qh][t][r]);
          mx = fmaxf(mx, __shfl_xor(mx, 16));
          mx = fmaxf(mx, __shfl_xor(mx, 32));
          const float mn = fmaxf(m_i[qh], mx);
          const float alpha = exp2f((m_i[qh] - mn) * SL);
          float rs = 0.f;
#pragma unroll
          for (int t = 0; t < 4; ++t) {
            float p0 = exp2f((s[qh][t][0] - mn) * SL);
            float p1 = exp2f((s[qh][t][1] - mn) * SL);
            float p2 = exp2f((s[qh][t][2] - mn) * SL);
            float p3 = exp2f((s[qh][t][3] - mn) * SL);
            rs += (p0 + p1) + (p2 + p3);
            ushort4 pw;
            pw.x = f2bf(p0); pw.y = f2bf(p1); pw.z = f2bf(p2); pw.w = f2bf(p3);
            *(ushort4*)(Pw + (qh * 16 + c) * 128 + poff[t]) = pw;
          }
          rs += __shfl_xor(rs, 16);
          rs += __shfl_xor(rs, 32);
          l_i[qh] = l_i[qh] * alpha + rs;
          m_i[qh] = mn;
#pragma unroll
          for (int r = 0; r < 4; ++r) ar[qh][r] = __shfl(alpha, 4 * g + r);
        }
#pragma unroll
        for (int qh = 0; qh < 2; ++qh)
#pragma unroll
          for (int cb = 0; cb < 8; ++cb)
#pragma unroll
            for (int r = 0; r < 4; ++r) acc[qh][cb][r] *= ar[qh][r];
        bf16x8 pa[2][2];
#pragma unroll
        for (int qh = 0; qh < 2; ++qh) {
          pa[qh][0] = *(const bf16x8*)(Pw + (qh * 16 + c) * 128 + voff[0]);
          pa[qh][1] = *(const bf16x8*)(Pw + (qh * 16 + c) * 128 + voff[1]);
        }
#pragma unroll
        for (int cb = 0; cb < 8; ++cb) {
          bf16x8 vf0 = *(const bf16x8*)(Vtl + cb * 2048 + c * 128 + voff[0]);
          bf16x8 vf1 = *(const bf16x8*)(Vtl + cb * 2048 + c * 128 + voff[1]);
          acc[0][cb] = __builtin_amdgcn_mfma_f32_16x16x32_bf16(pa[0][0], vf0, acc[0][cb], 0, 0, 0);
          acc[0][cb] = __builtin_amdgcn_mfma_f32_16x16x32_bf16(pa[0][1], vf1, acc[0][cb], 0, 0, 0);
          acc[1][cb] = __builtin_amdgcn_mfma_f32_16x16x32_bf16(pa[1][0], vf0, acc[1][cb], 0, 0, 0);
          acc[1][cb] = __builtin_amdgcn_mfma_f32_16x16x32_bf16(pa[1][1], vf1, acc[1][cb], 0, 0, 0);
        }
      }
      __syncthreads();
      cur ^= 1;
    }
#pragma unroll
    for (int qh = 0; qh < 2; ++qh) {
      float linv = 1.0f / l_i[qh];
      float lr[4];
#pragma unroll
      for (int r = 0; r < 4; ++r) lr[r] = __shfl(linv, 4 * g + r);
#pragma unroll
      for (int cb = 0; cb < 8; ++cb)
#pragma unroll
        for (int r = 0; r < 4; ++r) {
          int q = q0 + qh * 16 + 4 * g + r;
          O[(((size_t)b * S_LEN + q) * NH + h) * HD + cb * 16 + c] = f2bf(acc[qh][cb][r] * lr[r]);
        }
    }
  }
}

// ---------------------------------------------------------------------------
extern "C" void kernel_launch(void* const* d_in, const int* in_sizes, int n_in,
                              void* d_out, int out_size, void* d_ws, size_t ws_size,
                              hipStream_t stream) {
  const float* x    = (const float*)d_in[0];
  const float* wqkv = (const float*)d_in[1];
  const float* wo   = (const float*)d_in[2];
  float* out = (float*)d_out;
  char* ws = (char*)d_ws;

  u16*  xb    = (u16*)(ws + 0);            // reused as attn out later
  u16*  wqkvb = (u16*)(ws + 33554432);
  float* tab  = (float*)(ws + 58720256);   // live through gemm1 epilogue
  u16*  wob   = (u16*)(ws + 67108864);     // ex-qkvb region (free)
  u16*  Vt    = (u16*)(ws + 167772160);
  u16*  attn  = (u16*)(ws + 0);
  u16*  Qr = (u16*)d_out;                  // d_out scratch: dead before GEMM2
  u16*  Kr = (u16*)d_out + 16777216;

  // all conversions + RoPE table in one launch
  prep_all<<<33280, 256, 0, stream>>>(x, wqkv, wo, xb, wqkvb, wob, tab);

  // qkv = x @ wqkv^T fused with RoPE + V-transpose (768 blocks: 2+ blocks/CU TLP)
  gemm_fused<1, u16><<<768, 512, 0, stream>>>(xb, wqkvb, (u16*)nullptr, tab, Qr, Kr, Vt,
                                              8192, 6144, 2048, 24);

  attn_fwd<<<dim3(64, 4), 512, 0, stream>>>(Qr, Kr, Vt, attn);

  // out = attn @ wo^T
  gemm_fused<0, float><<<256, 512, 0, stream>>>(attn, wob, out, nullptr, nullptr, nullptr, nullptr,
                                                8192, 2048, 2048, 8);
}